// Round 14
// baseline (379.258 us; speedup 1.0000x reference)
//
#include <hip/hip_runtime.h>
#include <hip/hip_bf16.h>

// Problem constants: B=2, S=2048, D=1024, H=16, DH=64
typedef unsigned short u16;
typedef unsigned int u32;
typedef __attribute__((ext_vector_type(8))) short short8;
typedef __attribute__((ext_vector_type(4))) float f32x4;
typedef __attribute__((ext_vector_type(4))) u16 u16x4;
typedef __attribute__((ext_vector_type(4))) u32 u32x4;

__device__ __forceinline__ u16 f2bf(float f) {
  unsigned u = __builtin_bit_cast(unsigned, f);
  u = (u + 0x7FFFu + ((u >> 16) & 1u)) >> 16;  // RNE
  return (u16)u;
}

// v_cvt_pk_bf16_f32: packs bf16(lo), bf16(hi) into one u32
__device__ __forceinline__ u32 cvt_pk_bf16(float lo, float hi) {
  u32 r;
  asm("v_cvt_pk_bf16_f32 %0, %1, %2" : "=v"(r) : "v"(lo), "v"(hi));
  return r;
}

// async global->LDS, 16B per lane. LDS dest = base + lane*16 (linear, HW-fixed).
__device__ __forceinline__ void gload16(const void* g, void* l) {
  __builtin_amdgcn_global_load_lds(
      (const __attribute__((address_space(1))) void*)g,
      (__attribute__((address_space(3))) void*)l, 16, 0, 0);
}

// One fused f32->bf16 convert for all inputs; block 0 also zeroes the split-t
// pair counters (stream order guarantees this completes before attn_kernel).
__global__ __launch_bounds__(256) void cvt_all(
    const float* __restrict__ e, const float* __restrict__ wq,
    const float* __restrict__ wk, const float* __restrict__ wv,
    const float* __restrict__ w1, const float* __restrict__ w2,
    u16* __restrict__ ebf, u16* __restrict__ wqkv,
    u16* __restrict__ w1b, u16* __restrict__ w2b, u32* __restrict__ cnt)
{
  if (blockIdx.x == 0) {
    cnt[threadIdx.x] = 0;
    cnt[256 + threadIdx.x] = 0;
  }
  int i = blockIdx.x * 256 + threadIdx.x;   // float4 index
  const float* src;
  u16* dst;
  if (i < 1048576)       { src = e;  dst = ebf; }
  else if (i < 1310720)  { src = wq; dst = wqkv;           i -= 1048576; }
  else if (i < 1572864)  { src = wk; dst = wqkv + 1048576; i -= 1310720; }
  else if (i < 1835008)  { src = wv; dst = wqkv + 2097152; i -= 1572864; }
  else if (i < 2359296)  { src = w1; dst = w1b;            i -= 1835008; }
  else                   { src = w2; dst = w2b;            i -= 2359296; }
  const float4 v = reinterpret_cast<const float4*>(src)[i];
  u16x4 o = { f2bf(v.x), f2bf(v.y), f2bf(v.z), f2bf(v.w) };
  *reinterpret_cast<u16x4*>(dst + (size_t)i * 4) = o;
}

// C = A[M,K] @ W[N,K]^T, bf16 in / fp32 acc. Tile BM x 128, BK=64, 4 waves 2x2.
// Staging via global_load_lds w=16: LDS linear [rows][64], global source chunk
// pre-swizzled ch^(row&7); reads XOR with (c&7)  ->  conflict-free ds_read_b128.
// MODE 1: fused QKV. n<1024 -> Qh [B,H,S,DH] * qscale; n<2048 -> Kh [B,H,S,DH];
//         else -> Vt [B,H,DH,S'] + bias, t'-permuted per 32-group.
// MODE 3: +bias, ReLU, out bf16 [M,N]
// MODE 4: +bias, +resid fp32, out fp32 [M,N]
template<int MODE, int BM>
__global__ __launch_bounds__(256, 3) void gemm_bt(
    const u16* __restrict__ A, const u16* __restrict__ W,
    const float* __restrict__ bias, const float* __restrict__ resid,
    void* __restrict__ out0, void* __restrict__ out1, void* __restrict__ out2,
    int M, int N, int K)
{
  constexpr int II = BM / 32;                 // m-frags per wave
  __shared__ __align__(16) u16 At[BM * 64];
  __shared__ __align__(16) u16 Bt[128 * 64];
  const int tid = threadIdx.x, lane = tid & 63, wid = tid >> 6;
  const int g = lane >> 4, c = lane & 15;
  const int wr = (wid >> 1) * (BM / 2), wc = (wid & 1) * 64;
  const int m0 = blockIdx.y * BM, n0 = blockIdx.x * 128;
  const int lrow = lane >> 3;                 // 0..7 (row within 8-row stripe)
  const int lch = (lane & 7) ^ lrow;          // pre-swizzled source chunk
  const int rsw = c & 7;                      // read-side XOR

  f32x4 acc[II][4];
  #pragma unroll
  for (int i = 0; i < II; i++)
    #pragma unroll
    for (int j = 0; j < 4; j++)
      acc[i][j] = (f32x4){0.f, 0.f, 0.f, 0.f};

  const u16* Ab = A + (size_t)m0 * K;
  const u16* Wb = W + (size_t)n0 * K;

  for (int k0 = 0; k0 < K; k0 += 64) {
    __syncthreads();                          // prior iter's frag reads done
    #pragma unroll
    for (int i = 0; i < II; i++) {
      const int r0 = (wid * II + i) * 8;
      gload16(Ab + (size_t)(r0 + lrow) * K + k0 + lch * 8, &At[r0 * 64]);
    }
    #pragma unroll
    for (int i = 0; i < 4; i++) {
      const int r0 = (wid * 4 + i) * 8;
      gload16(Wb + (size_t)(r0 + lrow) * K + k0 + lch * 8, &Bt[r0 * 64]);
    }
    __syncthreads();                          // vmcnt(0) drained by compiler
    #pragma unroll
    for (int kh = 0; kh < 2; kh++) {
      short8 af[II], bw[4];
      #pragma unroll
      for (int i = 0; i < II; i++)
        af[i] = *reinterpret_cast<const short8*>(
            &At[(wr + i * 16 + c) * 64 + (((g + 4 * kh) ^ rsw) * 8)]);
      #pragma unroll
      for (int j = 0; j < 4; j++)
        bw[j] = *reinterpret_cast<const short8*>(
            &Bt[(wc + j * 16 + c) * 64 + (((g + 4 * kh) ^ rsw) * 8)]);
      #pragma unroll
      for (int i = 0; i < II; i++)
        #pragma unroll
        for (int j = 0; j < 4; j++)
          acc[i][j] = __builtin_amdgcn_mfma_f32_16x16x32_bf16(af[i], bw[j], acc[i][j], 0, 0, 0);
    }
  }

  #pragma unroll
  for (int i = 0; i < II; i++) {
    #pragma unroll
    for (int j = 0; j < 4; j++) {
      const int n = n0 + wc + j * 16 + c;
      const int mb = m0 + wr + i * 16 + g * 4;  // first of 4 consecutive rows
      if (MODE == 1) {
        const int seg = n >> 10, nn = n & 1023;
        const int h = nn >> 6, d = nn & 63;
        const int bb = mb >> 11, s = mb & 2047;
        if (seg == 2) {
          const float bval = bias[nn];
          u16x4 o;
          #pragma unroll
          for (int r = 0; r < 4; r++) o[r] = f2bf(acc[i][j][r] + bval);
          // t' permutation within 32-group (s is a multiple of 4)
          const int s32 = s & 31;
          const int t2 = (s & ~31) + ((s32 >> 2) & 3) * 8 + ((s32 >> 4) & 1) * 4;
          *reinterpret_cast<u16x4*>(reinterpret_cast<u16*>(out2) +
              ((size_t)((bb << 4) + h) * 64 + d) * 2048 + t2) = o;
        } else {
          u16* dst = reinterpret_cast<u16*>(seg ? out1 : out0);
          const float sc = seg ? 1.0f : 0.18033688f;  // log2(e)/sqrt(64) folded into Q
          #pragma unroll
          for (int r = 0; r < 4; r++)
            dst[((size_t)((bb << 4) + h) * 2048 + s + r) * 64 + d] = f2bf(acc[i][j][r] * sc);
        }
      } else if (MODE == 3) {
        const float bval = bias[n];
        #pragma unroll
        for (int r = 0; r < 4; r++) {
          float v = fmaxf(acc[i][j][r] + bval, 0.f);
          reinterpret_cast<u16*>(out0)[(size_t)(mb + r) * N + n] = f2bf(v);
        }
      } else {
        const float bval = bias[n];
        #pragma unroll
        for (int r = 0; r < 4; r++) {
          const int m = mb + r;
          reinterpret_cast<float*>(out0)[(size_t)m * N + n] =
              acc[i][j][r] + bval + resid[(size_t)m * N + n];
        }
      }
    }
  }
}

// Flash attention, swapped-QK^T, fixed-shift softmax, double-buffered K/V LDS,
// SPLIT-T 2-way with IN-KERNEL ATOMIC FINISHER: each block processes half the
// t-range; both blocks of a (bh,xq) pair write bf16 partials + f32 row-sums,
// __threadfence (device scope), then one atomicAdd on the pair counter. The
// SECOND arriver (own partial still in registers) reads only the peer's 16 KB
// partial, adds, normalizes, writes ao. No spin; output is order-independent
// (2-operand f32 add commutes). Grid 1024 (4 blocks/CU, 4 waves/SIMD),
// bijective XCD-chunked swizzle for K/V slab L2 locality.
__global__ __launch_bounds__(256, 4) void attn_kernel(
    const u16* __restrict__ Qh, const u16* __restrict__ Kh,
    const u16* __restrict__ Vt, u16* __restrict__ apart,
    float* __restrict__ lpart, u32* __restrict__ cnt, u16* __restrict__ ao)
{
  __shared__ __align__(16) u16 Kt[2][64 * 64];
  __shared__ __align__(16) u16 Vl[2][64 * 64];
  __shared__ u32 role;

  const int tid = threadIdx.x;
  const int lane = tid & 63, wid = tid >> 6;
  const int g = lane >> 4, c = lane & 15;

  // bijective XCD swizzle (1024 % 8 == 0): contiguous v-chunks per XCD
  const int v = (blockIdx.x & 7) * 128 + (blockIdx.x >> 3);
  const int half = v >> 9, rem = v & 511;
  const int bh = rem >> 4, xq = rem & 15;
  const int q0 = xq * 128 + wid * 32;
  const int tbase = half * 1024;

  const int lrow = lane >> 3;
  const int lch = (lane & 7) ^ lrow;
  const int rsw = c & 7;

  // Q as B-operand: n=q=c, k=dh contiguous (pre-scaled by log2(e)/8)
  short8 bq[2][2];
  #pragma unroll
  for (int qt = 0; qt < 2; qt++) {
    const u16* qrow = Qh + ((size_t)bh * 2048 + q0 + qt * 16 + c) * 64;
    bq[qt][0] = *reinterpret_cast<const short8*>(qrow + g * 8);
    bq[qt][1] = *reinterpret_cast<const short8*>(qrow + 32 + g * 8);
  }

  f32x4 acc[2][4];
  #pragma unroll
  for (int qt = 0; qt < 2; qt++)
    #pragma unroll
    for (int dt = 0; dt < 4; dt++)
      acc[qt][dt] = (f32x4){0.f, 0.f, 0.f, 0.f};
  f32x4 accl[2] = {(f32x4){0.f, 0.f, 0.f, 0.f}, (f32x4){0.f, 0.f, 0.f, 0.f}};
  const short8 ones = {0x3F80, 0x3F80, 0x3F80, 0x3F80, 0x3F80, 0x3F80, 0x3F80, 0x3F80};

  const u16* Kb = Kh + (size_t)bh * 2048 * 64;
  const u16* Vb = Vt + (size_t)bh * 64 * 2048;

  auto stage = [&](int buf, int t0) {
    #pragma unroll
    for (int i = 0; i < 2; i++) {
      const int r0 = (wid * 2 + i) * 8;
      gload16(Kb + (size_t)(t0 + r0 + lrow) * 64 + lch * 8, &Kt[buf][r0 * 64]);
    }
    #pragma unroll
    for (int i = 0; i < 2; i++) {
      const int r0 = (wid * 2 + i) * 8;
      gload16(Vb + (size_t)(r0 + lrow) * 2048 + t0 + lch * 8, &Vl[buf][r0 * 64]);
    }
  };

  stage(0, tbase);   // prologue: first tile of this half -> buf 0

  int cur = 0;
  for (int t0 = tbase; t0 < tbase + 1024; t0 += 64, cur ^= 1) {
    __syncthreads();   // buf[cur] ready (loads issued last iter); prev reads done
    if (t0 + 64 < tbase + 1024) stage(cur ^ 1, t0 + 64);

    #pragma unroll
    for (int cp = 0; cp < 2; cp++) {
      // S^T[t][q]: t = cp*32 + h*16 + g*4 + r, q = c  (already log2-domain)
      f32x4 sv[2][2];
      __builtin_amdgcn_s_setprio(1);
      #pragma unroll
      for (int h = 0; h < 2; h++) {
        const u16* kr = &Kt[cur][(cp * 32 + h * 16 + c) * 64];
        short8 ka  = *reinterpret_cast<const short8*>(kr + ((g ^ rsw) * 8));
        short8 ka2 = *reinterpret_cast<const short8*>(kr + (((g + 4) ^ rsw) * 8));
        #pragma unroll
        for (int qt = 0; qt < 2; qt++) {
          f32x4 z = (f32x4){0.f, 0.f, 0.f, 0.f};
          z = __builtin_amdgcn_mfma_f32_16x16x32_bf16(ka, bq[qt][0], z, 0, 0, 0);
          z = __builtin_amdgcn_mfma_f32_16x16x32_bf16(ka2, bq[qt][1], z, 0, 0, 0);
          sv[qt][h] = z;
        }
      }
      __builtin_amdgcn_s_setprio(0);

      // fixed-shift softmax: p = exp2(f); pack pairs to bf16 (PV A-frag order)
      short8 pk[2];
      #pragma unroll
      for (int qt = 0; qt < 2; qt++) {
        float p[8];
        #pragma unroll
        for (int i = 0; i < 8; i++)
          p[i] = __builtin_amdgcn_exp2f(sv[qt][i >> 2][i & 3]);
        u32x4 w;
        #pragma unroll
        for (int k = 0; k < 4; k++)
          w[k] = cvt_pk_bf16(p[2 * k], p[2 * k + 1]);
        pk[qt] = __builtin_bit_cast(short8, w);
      }

      // PV: A = P (in regs), B = V'^T rows, one b128 per (dt,cp);
      // l-sums ride the matrix pipe via the all-ones B operand.
      __builtin_amdgcn_s_setprio(1);
      #pragma unroll
      for (int dt = 0; dt < 4; dt++) {
        const short8 vf = *reinterpret_cast<const short8*>(
            &Vl[cur][(dt * 16 + c) * 64 + (((cp * 4 + g) ^ rsw) * 8)]);
        acc[0][dt] = __builtin_amdgcn_mfma_f32_16x16x32_bf16(pk[0], vf, acc[0][dt], 0, 0, 0);
        acc[1][dt] = __builtin_amdgcn_mfma_f32_16x16x32_bf16(pk[1], vf, acc[1][dt], 0, 0, 0);
      }
      accl[0] = __builtin_amdgcn_mfma_f32_16x16x32_bf16(pk[0], ones, accl[0], 0, 0, 0);
      accl[1] = __builtin_amdgcn_mfma_f32_16x16x32_bf16(pk[1], ones, accl[1], 0, 0, 0);
      __builtin_amdgcn_s_setprio(0);
    }
  }

  // ---- write own partial: apart [half][bh][q][64] bf16, lpart f32 ----
  u16* ob = apart + ((size_t)(half * 32 + bh) * 2048) * 64;
  #pragma unroll
  for (int qt = 0; qt < 2; qt++) {
    #pragma unroll
    for (int dt = 0; dt < 4; dt++)
      #pragma unroll
      for (int r = 0; r < 4; r++) {
        const size_t q = q0 + qt * 16 + g * 4 + r;
        ob[q * 64 + dt * 16 + c] = f2bf(acc[qt][dt][r]);
      }
    if (c == 0) {
      #pragma unroll
      for (int r = 0; r < 4; r++)
        lpart[(size_t)(half * 32 + bh) * 2048 + q0 + qt * 16 + g * 4 + r] = accl[qt][r];
    }
  }

  // ---- pair rendezvous: second arriver combines ----
  __threadfence();          // make this thread's stores device-visible
  __syncthreads();          // all threads fenced before the block's atomic
  if (tid == 0) role = atomicAdd(&cnt[rem], 1u);
  __syncthreads();
  if (role == 0) return;    // first arriver: peer will finish

  __threadfence();          // acquire: peer's stores are device-visible
  const u16* pb = apart + ((size_t)((1 - half) * 32 + bh) * 2048) * 64;
  const float* pl = lpart + (size_t)((1 - half) * 32 + bh) * 2048;
  u16* aob = ao + (size_t)(bh >> 4) * 2048 * 1024 + (bh & 15) * 64;
  #pragma unroll
  for (int qt = 0; qt < 2; qt++) {
    float lq[4];
    #pragma unroll
    for (int r = 0; r < 4; r++)
      lq[r] = 1.0f / (accl[qt][r] + pl[q0 + qt * 16 + g * 4 + r]);
    #pragma unroll
    for (int dt = 0; dt < 4; dt++)
      #pragma unroll
      for (int r = 0; r < 4; r++) {
        const size_t q = q0 + qt * 16 + g * 4 + r;
        const float peer = __builtin_bit_cast(
            float, (u32)pb[q * 64 + dt * 16 + c] << 16);
        aob[q * 1024 + dt * 16 + c] = f2bf((acc[qt][dt][r] + peer) * lq[r]);
      }
  }
}

extern "C" void kernel_launch(void* const* d_in, const int* in_sizes, int n_in,
                              void* d_out, int out_size, void* d_ws, size_t ws_size,
                              hipStream_t stream) {
  const float* embed = (const float*)d_in[0];
  const float* Wq = (const float*)d_in[1];
  const float* Wk = (const float*)d_in[2];
  const float* Wv = (const float*)d_in[3];
  const float* bv = (const float*)d_in[4];
  const float* W1 = (const float*)d_in[5];
  const float* b1 = (const float*)d_in[6];
  const float* W2 = (const float*)d_in[7];
  const float* b2 = (const float*)d_in[8];

  char* ws = (char*)d_ws;
  u16* ebf  = (u16*)ws;  ws += (size_t)4096 * 1024 * 2;  // embed bf16 [B*S, D]
  u16* wqkv = (u16*)ws;  ws += (size_t)3072 * 1024 * 2;  // packed [Wq;Wk;Wv]
  u16* w1b  = (u16*)ws;  ws += (size_t)2048 * 1024 * 2;
  u16* w2b  = (u16*)ws;  ws += (size_t)1024 * 2048 * 2;
  u16* Qh   = (u16*)ws;  ws += (size_t)4096 * 1024 * 2;  // [B,H,S,DH], pre-scaled
  u16* Kh   = (u16*)ws;  ws += (size_t)4096 * 1024 * 2;  // [B,H,S,DH]
  u16* Vt   = (u16*)ws;  ws += (size_t)4096 * 1024 * 2;  // [B,H,DH,S'] t'-permuted
  u16* ao   = (u16*)ws;  ws += (size_t)4096 * 1024 * 2;  // attn out bf16 [B*S, D]
  u16* h1   = (u16*)ws;  ws += (size_t)4096 * 2048 * 2;  // FFN hidden bf16 [B*S, 2D]
  u32* cnt  = (u32*)ws;  ws += 512 * 4;                  // split-t pair counters

  // Aliased partial buffers (dead regions at attn time):
  //   apart (16.8 MB) -> h1 region (FFN1 writes h1 only after attn completes)
  //   lpart (512 KB)  -> ebf region (ebf dead after the QKV GEMM)
  u16* apart = h1;
  float* lpart = (float*)ebf;

  dim3 blk(256);
  cvt_all<<<dim3(11264), blk, 0, stream>>>(embed, Wq, Wk, Wv, W1, W2,
                                           ebf, wqkv, w1b, w2b, cnt);
  gemm_bt<1, 128><<<dim3(24, 32), blk, 0, stream>>>(
      ebf, wqkv, bv, nullptr, Qh, Kh, Vt, 4096, 3072, 1024);
  attn_kernel<<<dim3(1024), blk, 0, stream>>>(Qh, Kh, Vt, apart, lpart, cnt, ao);
  gemm_bt<3, 128><<<dim3(16, 32), blk, 0, stream>>>(
      ao, w1b, b1, nullptr, h1, nullptr, nullptr, 4096, 2048, 1024);
  gemm_bt<4, 64><<<dim3(8, 64), blk, 0, stream>>>(
      h1, w2b, b2, embed, d_out, nullptr, nullptr, 4096, 1024, 2048);
}

// Round 15
// 141.568 us; speedup vs baseline: 2.6790x; 2.6790x over previous
//
#include <hip/hip_runtime.h>
#include <hip/hip_bf16.h>

// Problem constants: B=2, S=2048, D=1024, H=16, DH=64
typedef unsigned short u16;
typedef unsigned int u32;
typedef __attribute__((ext_vector_type(8))) short short8;
typedef __attribute__((ext_vector_type(4))) float f32x4;
typedef __attribute__((ext_vector_type(4))) u16 u16x4;
typedef __attribute__((ext_vector_type(4))) u32 u32x4;

__device__ __forceinline__ u16 f2bf(float f) {
  unsigned u = __builtin_bit_cast(unsigned, f);
  u = (u + 0x7FFFu + ((u >> 16) & 1u)) >> 16;  // RNE
  return (u16)u;
}

// v_cvt_pk_bf16_f32: packs bf16(lo), bf16(hi) into one u32
__device__ __forceinline__ u32 cvt_pk_bf16(float lo, float hi) {
  u32 r;
  asm("v_cvt_pk_bf16_f32 %0, %1, %2" : "=v"(r) : "v"(lo), "v"(hi));
  return r;
}

// async global->LDS, 16B per lane. LDS dest = base + lane*16 (linear, HW-fixed).
__device__ __forceinline__ void gload16(const void* g, void* l) {
  __builtin_amdgcn_global_load_lds(
      (const __attribute__((address_space(1))) void*)g,
      (__attribute__((address_space(3))) void*)l, 16, 0, 0);
}

// One fused f32->bf16 convert for all inputs. Segment f4-counts are multiples
// of 256 so every 256-thread block is segment-uniform.
__global__ __launch_bounds__(256) void cvt_all(
    const float* __restrict__ e, const float* __restrict__ wq,
    const float* __restrict__ wk, const float* __restrict__ wv,
    const float* __restrict__ w1, const float* __restrict__ w2,
    u16* __restrict__ ebf, u16* __restrict__ wqkv,
    u16* __restrict__ w1b, u16* __restrict__ w2b)
{
  int i = blockIdx.x * 256 + threadIdx.x;   // float4 index
  const float* src;
  u16* dst;
  if (i < 1048576)       { src = e;  dst = ebf; }
  else if (i < 1310720)  { src = wq; dst = wqkv;           i -= 1048576; }
  else if (i < 1572864)  { src = wk; dst = wqkv + 1048576; i -= 1310720; }
  else if (i < 1835008)  { src = wv; dst = wqkv + 2097152; i -= 1572864; }
  else if (i < 2359296)  { src = w1; dst = w1b;            i -= 1835008; }
  else                   { src = w2; dst = w2b;            i -= 2359296; }
  const float4 v = reinterpret_cast<const float4*>(src)[i];
  u16x4 o = { f2bf(v.x), f2bf(v.y), f2bf(v.z), f2bf(v.w) };
  *reinterpret_cast<u16x4*>(dst + (size_t)i * 4) = o;
}

// C = A[M,K] @ W[N,K]^T, bf16 in / fp32 acc. Tile BM x 128, BK=64, 4 waves 2x2.
// Staging via global_load_lds w=16: LDS linear [rows][64], global source chunk
// pre-swizzled ch^(row&7); reads XOR with (c&7)  ->  conflict-free ds_read_b128.
// MODE 1: fused QKV. n<1024 -> Qh [B,H,S,DH] * qscale; n<2048 -> Kh [B,H,S,DH];
//         else -> Vt [B,H,DH,S'] + bias, with t' MFMA-k-order permutation
//         within each 32-t group (t = h*16+g*4+b -> t' = g*8+h*4+b) so the
//         attention PV B-frag is one contiguous ds_read_b128.
// MODE 3: +bias, ReLU, out bf16 [M,N]
// MODE 4: +bias, +resid fp32, out fp32 [M,N]
template<int MODE, int BM>
__global__ __launch_bounds__(256, 3) void gemm_bt(
    const u16* __restrict__ A, const u16* __restrict__ W,
    const float* __restrict__ bias, const float* __restrict__ resid,
    void* __restrict__ out0, void* __restrict__ out1, void* __restrict__ out2,
    int M, int N, int K)
{
  constexpr int II = BM / 32;                 // m-frags per wave
  __shared__ __align__(16) u16 At[BM * 64];
  __shared__ __align__(16) u16 Bt[128 * 64];
  const int tid = threadIdx.x, lane = tid & 63, wid = tid >> 6;
  const int g = lane >> 4, c = lane & 15;
  const int wr = (wid >> 1) * (BM / 2), wc = (wid & 1) * 64;
  const int m0 = blockIdx.y * BM, n0 = blockIdx.x * 128;
  const int lrow = lane >> 3;                 // 0..7 (row within 8-row stripe)
  const int lch = (lane & 7) ^ lrow;          // pre-swizzled source chunk
  const int rsw = c & 7;                      // read-side XOR

  f32x4 acc[II][4];
  #pragma unroll
  for (int i = 0; i < II; i++)
    #pragma unroll
    for (int j = 0; j < 4; j++)
      acc[i][j] = (f32x4){0.f, 0.f, 0.f, 0.f};

  const u16* Ab = A + (size_t)m0 * K;
  const u16* Wb = W + (size_t)n0 * K;

  for (int k0 = 0; k0 < K; k0 += 64) {
    __syncthreads();                          // prior iter's frag reads done
    #pragma unroll
    for (int i = 0; i < II; i++) {
      const int r0 = (wid * II + i) * 8;
      gload16(Ab + (size_t)(r0 + lrow) * K + k0 + lch * 8, &At[r0 * 64]);
    }
    #pragma unroll
    for (int i = 0; i < 4; i++) {
      const int r0 = (wid * 4 + i) * 8;
      gload16(Wb + (size_t)(r0 + lrow) * K + k0 + lch * 8, &Bt[r0 * 64]);
    }
    __syncthreads();                          // vmcnt(0) drained by compiler
    #pragma unroll
    for (int kh = 0; kh < 2; kh++) {
      short8 af[II], bw[4];
      #pragma unroll
      for (int i = 0; i < II; i++)
        af[i] = *reinterpret_cast<const short8*>(
            &At[(wr + i * 16 + c) * 64 + (((g + 4 * kh) ^ rsw) * 8)]);
      #pragma unroll
      for (int j = 0; j < 4; j++)
        bw[j] = *reinterpret_cast<const short8*>(
            &Bt[(wc + j * 16 + c) * 64 + (((g + 4 * kh) ^ rsw) * 8)]);
      #pragma unroll
      for (int i = 0; i < II; i++)
        #pragma unroll
        for (int j = 0; j < 4; j++)
          acc[i][j] = __builtin_amdgcn_mfma_f32_16x16x32_bf16(af[i], bw[j], acc[i][j], 0, 0, 0);
    }
  }

  #pragma unroll
  for (int i = 0; i < II; i++) {
    #pragma unroll
    for (int j = 0; j < 4; j++) {
      const int n = n0 + wc + j * 16 + c;
      const int mb = m0 + wr + i * 16 + g * 4;  // first of 4 consecutive rows
      if (MODE == 1) {
        const int seg = n >> 10, nn = n & 1023;
        const int h = nn >> 6, d = nn & 63;
        const int bb = mb >> 11, s = mb & 2047;
        if (seg == 2) {
          const float bval = bias[nn];
          u16x4 o;
          #pragma unroll
          for (int r = 0; r < 4; r++) o[r] = f2bf(acc[i][j][r] + bval);
          // t' permutation within 32-group (s is a multiple of 4)
          const int s32 = s & 31;
          const int t2 = (s & ~31) + ((s32 >> 2) & 3) * 8 + ((s32 >> 4) & 1) * 4;
          *reinterpret_cast<u16x4*>(reinterpret_cast<u16*>(out2) +
              ((size_t)((bb << 4) + h) * 64 + d) * 2048 + t2) = o;
        } else {
          u16* dst = reinterpret_cast<u16*>(seg ? out1 : out0);
          const float sc = seg ? 1.0f : 0.18033688f;  // log2(e)/sqrt(64) folded into Q
          #pragma unroll
          for (int r = 0; r < 4; r++)
            dst[((size_t)((bb << 4) + h) * 2048 + s + r) * 64 + d] = f2bf(acc[i][j][r] * sc);
        }
      } else if (MODE == 3) {
        const float bval = bias[n];
        #pragma unroll
        for (int r = 0; r < 4; r++) {
          float v = fmaxf(acc[i][j][r] + bval, 0.f);
          reinterpret_cast<u16*>(out0)[(size_t)(mb + r) * N + n] = f2bf(v);
        }
      } else {
        const float bval = bias[n];
        #pragma unroll
        for (int r = 0; r < 4; r++) {
          const int m = mb + r;
          reinterpret_cast<float*>(out0)[(size_t)m * N + n] =
              acc[i][j][r] + bval + resid[(size_t)m * N + n];
        }
      }
    }
  }
}

// Flash attention, swapped-QK^T, fixed-shift softmax, double-buffered K/V LDS,
// KVBLK=128 (half the barriers of the 64-t version; 2x MFMA per phase).
// grid (S/128, B*H), 4 waves; each wave owns 32 q-rows (2 q-tiles of 16):
// K/V-frags shared across both q-tiles; row-sums ride the matrix pipe via an
// all-ones B operand. V^T stored t'-permuted so each PV B-frag is one
// contiguous ds_read_b128. LDS 64 KB (2 x (K 16KB + V 16KB)).
// V tile rows are 256B (16 chunks): store chunk (lane&15)^(row&7) via
// pre-swizzled global source; read chunk (cp*4+g)^(c&7) -- same involution.
__global__ __launch_bounds__(256, 2) void attn_kernel(
    const u16* __restrict__ Qh, const u16* __restrict__ Kh,
    const u16* __restrict__ Vt, u16* __restrict__ ao)
{
  __shared__ __align__(16) u16 Kt[2][128 * 64];
  __shared__ __align__(16) u16 Vl[2][64 * 128];

  const int tid = threadIdx.x;
  const int lane = tid & 63, wid = tid >> 6;
  const int g = lane >> 4, c = lane & 15;
  const int bh = blockIdx.y;
  const int q0 = blockIdx.x * 128 + wid * 32;
  const int lrow = lane >> 3;
  const int lch = (lane & 7) ^ lrow;
  const int rsw = c & 7;

  // Q as B-operand: n=q=c, k=dh contiguous (pre-scaled by log2(e)/8)
  short8 bq[2][2];
  #pragma unroll
  for (int qt = 0; qt < 2; qt++) {
    const u16* qrow = Qh + ((size_t)bh * 2048 + q0 + qt * 16 + c) * 64;
    bq[qt][0] = *reinterpret_cast<const short8*>(qrow + g * 8);
    bq[qt][1] = *reinterpret_cast<const short8*>(qrow + 32 + g * 8);
  }

  f32x4 acc[2][4];
  #pragma unroll
  for (int qt = 0; qt < 2; qt++)
    #pragma unroll
    for (int dt = 0; dt < 4; dt++)
      acc[qt][dt] = (f32x4){0.f, 0.f, 0.f, 0.f};
  f32x4 accl[2] = {(f32x4){0.f, 0.f, 0.f, 0.f}, (f32x4){0.f, 0.f, 0.f, 0.f}};
  const short8 ones = {0x3F80, 0x3F80, 0x3F80, 0x3F80, 0x3F80, 0x3F80, 0x3F80, 0x3F80};

  const u16* Kb = Kh + (size_t)bh * 2048 * 64;
  const u16* Vb = Vt + (size_t)bh * 64 * 2048;

  auto stage = [&](int buf, int t0) {
    // K: 128 rows x 64 dh (8 chunks/row), 4 gloads/wave
    #pragma unroll
    for (int i = 0; i < 4; i++) {
      const int r0 = (wid * 4 + i) * 8;
      gload16(Kb + (size_t)(t0 + r0 + lrow) * 64 + lch * 8, &Kt[buf][r0 * 64]);
    }
    // V: 64 d-rows x 128 t' (16 chunks/row), 4 rows per gload, 4 gloads/wave
    #pragma unroll
    for (int i = 0; i < 4; i++) {
      const int r0 = wid * 16 + i * 4;
      const int vrow = r0 + (lane >> 4);
      const int vch = (lane & 15) ^ (vrow & 7);
      gload16(Vb + (size_t)vrow * 2048 + t0 + vch * 8, &Vl[buf][r0 * 128]);
    }
  };

  stage(0, 0);   // prologue: tile 0 -> buf 0

  int cur = 0;
  for (int t0 = 0; t0 < 2048; t0 += 128, cur ^= 1) {
    __syncthreads();   // buf[cur] ready (loads issued last iter); prev reads done
    if (t0 + 128 < 2048) stage(cur ^ 1, t0 + 128);

    #pragma unroll
    for (int cp = 0; cp < 4; cp++) {
      // S^T[t][q]: t = cp*32 + h*16 + g*4 + r, q = c  (already log2-domain)
      f32x4 sv[2][2];
      __builtin_amdgcn_s_setprio(1);
      #pragma unroll
      for (int h = 0; h < 2; h++) {
        const u16* kr = &Kt[cur][(cp * 32 + h * 16 + c) * 64];
        short8 ka  = *reinterpret_cast<const short8*>(kr + ((g ^ rsw) * 8));
        short8 ka2 = *reinterpret_cast<const short8*>(kr + (((g + 4) ^ rsw) * 8));
        #pragma unroll
        for (int qt = 0; qt < 2; qt++) {
          f32x4 z = (f32x4){0.f, 0.f, 0.f, 0.f};
          z = __builtin_amdgcn_mfma_f32_16x16x32_bf16(ka, bq[qt][0], z, 0, 0, 0);
          z = __builtin_amdgcn_mfma_f32_16x16x32_bf16(ka2, bq[qt][1], z, 0, 0, 0);
          sv[qt][h] = z;
        }
      }
      __builtin_amdgcn_s_setprio(0);

      // fixed-shift softmax: p = exp2(f); pack pairs to bf16 (PV A-frag order)
      short8 pk[2];
      #pragma unroll
      for (int qt = 0; qt < 2; qt++) {
        float p[8];
        #pragma unroll
        for (int i = 0; i < 8; i++)
          p[i] = __builtin_amdgcn_exp2f(sv[qt][i >> 2][i & 3]);
        u32x4 w;
        #pragma unroll
        for (int k = 0; k < 4; k++)
          w[k] = cvt_pk_bf16(p[2 * k], p[2 * k + 1]);
        pk[qt] = __builtin_bit_cast(short8, w);
      }

      // PV: A = P (in regs), B = V'^T rows, one b128 per (dt,cp);
      // l-sums ride the matrix pipe via the all-ones B operand.
      __builtin_amdgcn_s_setprio(1);
      #pragma unroll
      for (int dt = 0; dt < 4; dt++) {
        const short8 vf = *reinterpret_cast<const short8*>(
            &Vl[cur][(dt * 16 + c) * 128 + (((cp * 4 + g) ^ rsw) * 8)]);
        acc[0][dt] = __builtin_amdgcn_mfma_f32_16x16x32_bf16(pk[0], vf, acc[0][dt], 0, 0, 0);
        acc[1][dt] = __builtin_amdgcn_mfma_f32_16x16x32_bf16(pk[1], vf, acc[1][dt], 0, 0, 0);
      }
      accl[0] = __builtin_amdgcn_mfma_f32_16x16x32_bf16(pk[0], ones, accl[0], 0, 0, 0);
      accl[1] = __builtin_amdgcn_mfma_f32_16x16x32_bf16(pk[1], ones, accl[1], 0, 0, 0);
      __builtin_amdgcn_s_setprio(0);
    }
  }

  // finalize: accl[qt][r] = l for q-row g*4+r (already broadcast per lane)
  u16* ob = ao + (size_t)(bh >> 4) * 2048 * 1024 + (bh & 15) * 64;
  #pragma unroll
  for (int qt = 0; qt < 2; qt++) {
    float lq[4];
    #pragma unroll
    for (int r = 0; r < 4; r++) lq[r] = 1.0f / accl[qt][r];
    #pragma unroll
    for (int dt = 0; dt < 4; dt++)
      #pragma unroll
      for (int r = 0; r < 4; r++) {
        const size_t q = q0 + qt * 16 + g * 4 + r;
        ob[q * 1024 + dt * 16 + c] = f2bf(acc[qt][dt][r] * lq[r]);
      }
  }
}

extern "C" void kernel_launch(void* const* d_in, const int* in_sizes, int n_in,
                              void* d_out, int out_size, void* d_ws, size_t ws_size,
                              hipStream_t stream) {
  const float* embed = (const float*)d_in[0];
  const float* Wq = (const float*)d_in[1];
  const float* Wk = (const float*)d_in[2];
  const float* Wv = (const float*)d_in[3];
  const float* bv = (const float*)d_in[4];
  const float* W1 = (const float*)d_in[5];
  const float* b1 = (const float*)d_in[6];
  const float* W2 = (const float*)d_in[7];
  const float* b2 = (const float*)d_in[8];

  char* ws = (char*)d_ws;
  u16* ebf  = (u16*)ws;  ws += (size_t)4096 * 1024 * 2;  // embed bf16 [B*S, D]
  u16* wqkv = (u16*)ws;  ws += (size_t)3072 * 1024 * 2;  // packed [Wq;Wk;Wv]
  u16* w1b  = (u16*)ws;  ws += (size_t)2048 * 1024 * 2;
  u16* w2b  = (u16*)ws;  ws += (size_t)1024 * 2048 * 2;
  u16* Qh   = (u16*)ws;  ws += (size_t)4096 * 1024 * 2;  // [B,H,S,DH], pre-scaled
  u16* Kh   = (u16*)ws;  ws += (size_t)4096 * 1024 * 2;  // [B,H,S,DH]
  u16* Vt   = (u16*)ws;  ws += (size_t)4096 * 1024 * 2;  // [B,H,DH,S'] t'-permuted
  u16* ao   = (u16*)ws;  ws += (size_t)4096 * 1024 * 2;  // attn out bf16 [B*S, D]
  u16* h1   = (u16*)ws;  ws += (size_t)4096 * 2048 * 2;  // FFN hidden bf16 [B*S, 2D]

  dim3 blk(256);
  cvt_all<<<dim3(11264), blk, 0, stream>>>(embed, Wq, Wk, Wv, W1, W2,
                                           ebf, wqkv, w1b, w2b);
  gemm_bt<1, 128><<<dim3(24, 32), blk, 0, stream>>>(
      ebf, wqkv, bv, nullptr, Qh, Kh, Vt, 4096, 3072, 1024);
  attn_kernel<<<dim3(16, 32), blk, 0, stream>>>(Qh, Kh, Vt, ao);
  gemm_bt<3, 128><<<dim3(16, 32), blk, 0, stream>>>(
      ao, w1b, b1, nullptr, h1, nullptr, nullptr, 4096, 2048, 1024);
  gemm_bt<4, 64><<<dim3(8, 64), blk, 0, stream>>>(
      h1, w2b, b2, embed, d_out, nullptr, nullptr, 4096, 1024, 2048);
}